// Round 12
// baseline (53.713 us; speedup 1.0000x reference)
//
#include <hip/hip_runtime.h>

#define HH  480
#define WW  480
#define ZZ  2
#define CC  64
#define CIN 4
#define BN_EPS 1e-3f
#define ROWS   (2 * ZZ * HH)    // B*Z*H = 1920 point rows
#define MAXR   256              // max points per row (fixed input: ~45 actual)
#define HCHUNK 16               // h-rows per pass-B block (1 channel) = 30KB linear
#define TPAD   484              // per-h-row tile stride: f4-aligned, bank-spread

// ---------------- K1: clear rowcnt (1920 ints) -------------------------------
__global__ __launch_bounds__(256) void pfn_clear_cnt(int* __restrict__ rowcnt)
{
    int i = blockIdx.x * blockDim.x + threadIdx.x;
    if (i < ROWS) rowcnt[i] = 0;
}

// ---------------- Pass A: widened — grid (ceil(B*N/256), 8) ------------------
__global__ __launch_bounds__(256) void pfn_pass_a(
    const float* __restrict__ feats,   // [B, N, 4]
    const int*   __restrict__ coords,  // [B, N, 3]
    const float* __restrict__ W,       // [64, 4]
    const float* __restrict__ gamma,
    const float* __restrict__ beta,
    const float* __restrict__ rmean,
    const float* __restrict__ rvar,
    float*  __restrict__ out0,         // [B, 64, N]
    float4* __restrict__ rowf4,        // [ROWS, MAXR] point features
    int*    __restrict__ roww,         // [ROWS, MAXR] point w (=cy)
    int*    __restrict__ rowcnt,       // [ROWS]
    int N, int B)
{
    int pt = blockIdx.x * blockDim.x + threadIdx.x;
    if (pt >= B * N) return;
    int n = pt % N;
    int b = pt / N;
    const int c0 = blockIdx.y * 8;

    float4 f = *reinterpret_cast<const float4*>(feats + (long)pt * CIN);

    #pragma unroll
    for (int k = 0; k < 8; ++k) {
        int c = c0 + k;
        float scale = gamma[c] * rsqrtf(rvar[c] + BN_EPS);
        float bias  = beta[c] - rmean[c] * scale;
        float v = f.x * W[c*4+0] + f.y * W[c*4+1] + f.z * W[c*4+2] + f.w * W[c*4+3];
        v = fmaxf(v * scale + bias, 0.0f);
        out0[((long)(b * CC + c)) * N + n] = v;   // lanes walk n: coalesced
    }

    if (blockIdx.y == 0) {
        int cx = coords[(long)pt*3 + 0];
        int cy = coords[(long)pt*3 + 1];
        int cz = coords[(long)pt*3 + 2];
        int row = (b * ZZ + cz) * HH + cx;        // point row (b,z,h)
        int k = atomicAdd(&rowcnt[row], 1);       // order nondet; max commutative
        if (k < MAXR) {
            rowf4[(long)row * MAXR + k] = f;
            roww [(long)row * MAXR + k] = cy;
        }
    }
}

// ---------------- Pass B: one block = one 30KB LINEAR chunk of out1 ----------
// bid = chunk index: (bz, c, hchunk) in exact memory order; consecutive blocks
// cover out1 in pure address order -> fill-shaped write stream / L2 eviction.
__global__ __launch_bounds__(256) void pfn_pass_b(
    const float4* __restrict__ rowf4,
    const int*    __restrict__ roww,
    const int*    __restrict__ rowcnt,
    const float*  __restrict__ W,
    const float*  __restrict__ gamma,
    const float*  __restrict__ beta,
    const float*  __restrict__ rmean,
    const float*  __restrict__ rvar,
    float* __restrict__ out1)          // [B, Z, 64, H, W]
{
    const int bid = blockIdx.x;                   // 0..7679
    const int hc  = bid % 30;                     // h-chunk within (bz,c)
    const int cl  = bid / 30;                     // (bz*64 + c), 0..255
    const int c   = cl & 63;
    const int bz  = cl >> 6;                      // b*ZZ+z, 0..3
    const int row0 = bz * HH + hc * HCHUNK;       // 16 point rows, same (b,z)
    const int tid = threadIdx.x;

    __shared__ float tile[HCHUNK][TPAD];          // 31 KB
    __shared__ int scnt[HCHUNK], pref[HCHUNK + 1];
    __shared__ unsigned char rowmap[HCHUNK * MAXR];  // 4 KB: flat idx -> row

    // zero tile: 1936 float4, 8 predicated unrolled iterations
    float4* t4 = reinterpret_cast<float4*>(&tile[0][0]);
    #pragma unroll
    for (int r = 0; r < 8; ++r) {
        int i = tid + r * 256;
        if (i < HCHUNK * TPAD / 4) t4[i] = make_float4(0.f, 0.f, 0.f, 0.f);
    }
    if (tid < HCHUNK) {
        int cn = rowcnt[row0 + tid];
        scnt[tid] = cn < MAXR ? cn : MAXR;
    }
    __syncthreads();
    if (tid == 0) {
        int acc = 0;
        #pragma unroll
        for (int r = 0; r < HCHUNK; ++r) { pref[r] = acc; acc += scnt[r]; }
        pref[HCHUNK] = acc;
    }
    __syncthreads();
    if (tid < HCHUNK) {
        int p0 = pref[tid], cn = scnt[tid];
        for (int j = 0; j < cn; ++j) rowmap[p0 + j] = (unsigned char)tid;
    }
    __syncthreads();

    // block-uniform channel constants (scalar path)
    const float w0 = W[c*4+0], w1 = W[c*4+1], w2 = W[c*4+2], w3 = W[c*4+3];
    const float sc = gamma[c] * rsqrtf(rvar[c] + BN_EPS);
    const float bi = beta[c] - rmean[c] * sc;

    // gather: flat point index across the 16 rows; each op = 1 point x 1 chan
    const int T = pref[HCHUNK];                   // ~336 actual
    for (int i = tid; i < T; i += 256) {
        int r  = rowmap[i];
        int jj = i - pref[r];
        long rb = (long)(row0 + r) * MAXR + jj;
        float4 f = rowf4[rb];
        int    w = roww [rb];
        float v = f.x*w0 + f.y*w1 + f.z*w2 + f.w*w3;
        v = fmaxf(v * sc + bi, 0.0f);
        // uint max == float max for non-negative floats; tile zero-init
        atomicMax(reinterpret_cast<unsigned int*>(&tile[r][w]), __float_as_uint(v));
    }
    __syncthreads();

    // readout: 1920 float4, written as ONE contiguous 30720B span:
    // out1_f4[bid*1920 + g], lanes walk g -> perfect sequential coverage
    float4* out_f4 = reinterpret_cast<float4*>(out1) + (long)bid * (HCHUNK * WW / 4);
    #pragma unroll
    for (int rr = 0; rr < 8; ++rr) {
        int g = tid + rr * 256;                   // 0..1919 (last iter: half)
        if (g < HCHUNK * WW / 4) {
            int hl = g / 120;                     // h-row within chunk
            int w4 = g - hl * 120;
            out_f4[g] = *reinterpret_cast<const float4*>(&tile[hl][w4 * 4]);
        }
    }
}

// ---------------- Fallback (round-1 path) if ws too small --------------------
__global__ __launch_bounds__(256) void pfn_fallback(
    const float* __restrict__ feats, const int* __restrict__ coords,
    const float* __restrict__ W, const float* __restrict__ gamma,
    const float* __restrict__ beta, const float* __restrict__ rmean,
    const float* __restrict__ rvar, float* __restrict__ out0,
    float* __restrict__ out1, int N, int B)
{
    long gid = (long)blockIdx.x * blockDim.x + threadIdx.x;
    long total = (long)CC * B * N;
    if (gid >= total) return;
    int n = (int)(gid % N); int rem = (int)(gid / N);
    int b = rem % B; int c = rem / B;
    long pt = (long)b * N + n;
    float4 f = *reinterpret_cast<const float4*>(feats + pt * CIN);
    float scale = gamma[c] * rsqrtf(rvar[c] + BN_EPS);
    float bias  = beta[c] - rmean[c] * scale;
    float val = f.x*W[c*4] + f.y*W[c*4+1] + f.z*W[c*4+2] + f.w*W[c*4+3];
    val = fmaxf(val * scale + bias, 0.0f);
    out0[((long)(b * CC + c)) * N + n] = val;
    int cx = coords[pt*3+0], cy = coords[pt*3+1], cz = coords[pt*3+2];
    long o1 = ((((long)(b * ZZ + cz)) * CC + c) * HH + cx) * WW + cy;
    atomicMax(reinterpret_cast<unsigned int*>(out1) + o1, __float_as_uint(val));
}

extern "C" void kernel_launch(void* const* d_in, const int* in_sizes, int n_in,
                              void* d_out, int out_size, void* d_ws, size_t ws_size,
                              hipStream_t stream) {
    const float* feats  = (const float*)d_in[0];
    const int*   coords = (const int*)d_in[1];
    const float* W      = (const float*)d_in[2];
    const float* gamma  = (const float*)d_in[3];
    const float* beta   = (const float*)d_in[4];
    const float* rmean  = (const float*)d_in[5];
    const float* rvar   = (const float*)d_in[6];

    const int B = 2;
    const int N = in_sizes[0] / (B * CIN);        // 20000

    float* out0 = (float*)d_out;
    long   out0_sz = (long)B * CC * N;
    float* out1 = out0 + out0_sz;

    // ws layout: rowf4 [ROWS*MAXR] float4 | roww [ROWS*MAXR] int | rowcnt [ROWS] int
    const size_t rowf4_bytes = (size_t)ROWS * MAXR * sizeof(float4);  // 7.86 MB
    const size_t roww_bytes  = (size_t)ROWS * MAXR * sizeof(int);     // 1.97 MB
    const size_t cnt_bytes   = (size_t)ROWS * sizeof(int);            // 7.7 KB
    const size_t need = rowf4_bytes + roww_bytes + cnt_bytes;

    if (ws_size >= need) {
        float4* rowf4  = (float4*)d_ws;
        int*    roww   = (int*)((char*)d_ws + rowf4_bytes);
        int*    rowcnt = (int*)((char*)d_ws + rowf4_bytes + roww_bytes);

        pfn_clear_cnt<<<(ROWS + 255) / 256, 256, 0, stream>>>(rowcnt);

        dim3 gridA((B * N + 255) / 256, 8);       // 157 x 8 = 1256 blocks
        pfn_pass_a<<<gridA, 256, 0, stream>>>(
            feats, coords, W, gamma, beta, rmean, rvar, out0,
            rowf4, roww, rowcnt, N, B);

        int blocksB = 2 * ZZ * CC * (HH / HCHUNK);  // 4*64*30 = 7680 chunks
        pfn_pass_b<<<blocksB, 256, 0, stream>>>(
            rowf4, roww, rowcnt, W, gamma, beta, rmean, rvar, out1);
    } else {
        size_t out1_bytes = (size_t)B * ZZ * CC * HH * WW * sizeof(float);
        (void)hipMemsetAsync(out1, 0, out1_bytes, stream);
        long total = (long)CC * B * N;
        pfn_fallback<<<(int)((total + 255) / 256), 256, 0, stream>>>(
            feats, coords, W, gamma, beta, rmean, rvar, out0, out1, N, B);
    }
}

// Round 13
// 51.821 us; speedup vs baseline: 1.0365x; 1.0365x over previous
//
#include <hip/hip_runtime.h>

#define HH  480
#define WW  480
#define ZZ  2
#define CC  64
#define CIN 4
#define BN_EPS 1e-3f
#define ROWS  (2 * ZZ * HH)     // B*Z*H = 1920 point rows
#define MAXR  256               // max points per row (fixed input: ~45 actual)
#define CTB   8                 // channels per chunk
#define TPAD  484               // tile row stride: f4-aligned, bank-spread

// ---------------- K1: clear rowcnt (1920 ints) -------------------------------
__global__ __launch_bounds__(256) void pfn_clear_cnt(int* __restrict__ rowcnt)
{
    int i = blockIdx.x * blockDim.x + threadIdx.x;
    if (i < ROWS) rowcnt[i] = 0;
}

// ---------------- Pass A: widened — grid (ceil(B*N/256), 8) ------------------
__global__ __launch_bounds__(256) void pfn_pass_a(
    const float* __restrict__ feats,   // [B, N, 4]
    const int*   __restrict__ coords,  // [B, N, 3]
    const float* __restrict__ W,       // [64, 4]
    const float* __restrict__ gamma,
    const float* __restrict__ beta,
    const float* __restrict__ rmean,
    const float* __restrict__ rvar,
    float*  __restrict__ out0,         // [B, 64, N]
    float4* __restrict__ rowf4,        // [ROWS, MAXR] point features
    int*    __restrict__ roww,         // [ROWS, MAXR] point w (=cy)
    int*    __restrict__ rowcnt,       // [ROWS]
    int N, int B)
{
    int pt = blockIdx.x * blockDim.x + threadIdx.x;
    if (pt >= B * N) return;
    int n = pt % N;
    int b = pt / N;
    const int c0 = blockIdx.y * 8;

    float4 f = *reinterpret_cast<const float4*>(feats + (long)pt * CIN);

    #pragma unroll
    for (int k = 0; k < 8; ++k) {
        int c = c0 + k;
        float scale = gamma[c] * rsqrtf(rvar[c] + BN_EPS);
        float bias  = beta[c] - rmean[c] * scale;
        float v = f.x * W[c*4+0] + f.y * W[c*4+1] + f.z * W[c*4+2] + f.w * W[c*4+3];
        v = fmaxf(v * scale + bias, 0.0f);
        out0[((long)(b * CC + c)) * N + n] = v;   // lanes walk n: coalesced
    }

    if (blockIdx.y == 0) {
        int cx = coords[(long)pt*3 + 0];
        int cy = coords[(long)pt*3 + 1];
        int cz = coords[(long)pt*3 + 2];
        int row = (b * ZZ + cz) * HH + cx;        // point row (b,z,h)
        int k = atomicAdd(&rowcnt[row], 1);       // order nondet; max commutative
        if (k < MAXR) {
            rowf4[(long)row * MAXR + k] = f;
            roww [(long)row * MAXR + k] = cy;
        }
    }
}

// ---------------- Pass B: persistent pipelined; row-points in registers ------
// block = (row, c-half): 4 chunks of 8 channels, double-buffered 15.5KB tiles.
// Point data loaded ONCE into registers; per chunk: stores(tile[a]) overlap
// zero(tile[b]) + register-sourced gather(tile[b]) -> store pipe stays fed.
__global__ __launch_bounds__(256) void pfn_pass_b(
    const float4* __restrict__ rowf4,
    const int*    __restrict__ roww,
    const int*    __restrict__ rowcnt,
    const float*  __restrict__ W,
    const float*  __restrict__ gamma,
    const float*  __restrict__ beta,
    const float*  __restrict__ rmean,
    const float*  __restrict__ rvar,
    float* __restrict__ out1)          // [B, Z, 64, H, W]
{
    const int bid = blockIdx.x;                   // 0..3839
    const int row = bid >> 1;                     // consecutive rows adjacent
    const int cq  = (bid & 1) * 4;                // chunk base: 0 or 4 (x8 ch)
    const int h  = row % HH;
    const int z  = (row / HH) % ZZ;
    const int b  = row / (HH * ZZ);
    const int tid = threadIdx.x;

    __shared__ float tile[2][CTB * TPAD];         // 2 x 15.5 KB -> 5 blk/CU

    // ---- load row's points into registers (one point per thread) ----
    int cnt = rowcnt[row];
    cnt = cnt < MAXR ? cnt : MAXR;
    float4 pf = make_float4(0.f, 0.f, 0.f, 0.f);
    int    pw = 0;
    if (tid < cnt) {
        pf = rowf4[(long)row * MAXR + tid];
        pw = roww [(long)row * MAXR + tid];
    }

    // ---- zero buf0 ----
    {
        float4* t4 = reinterpret_cast<float4*>(tile[0]);
        #pragma unroll
        for (int r = 0; r < 4; ++r) {
            int i = tid + r * 256;
            if (i < CTB * TPAD / 4) t4[i] = make_float4(0.f, 0.f, 0.f, 0.f);
        }
    }
    __syncthreads();

    // ---- G(0): register-sourced gather into buf0 ----
    if (tid < cnt) {
        #pragma unroll
        for (int j = 0; j < 8; ++j) {
            int c = (cq + 0) * 8 + j;             // uniform across lanes
            float sc = gamma[c] * rsqrtf(rvar[c] + BN_EPS);
            float bi = beta[c] - rmean[c] * sc;
            float v = pf.x*W[c*4+0] + pf.y*W[c*4+1] + pf.z*W[c*4+2] + pf.w*W[c*4+3];
            v = fmaxf(v * sc + bi, 0.0f);
            atomicMax(reinterpret_cast<unsigned int*>(&tile[0][j * TPAD + pw]),
                      __float_as_uint(v));
        }
    }
    __syncthreads();

    const long plane = (long)HH * WW;
    const int  ch = tid >> 5;                     // 0..7 (channel within chunk)
    const int  wl = tid & 31;                     // w4 = wl + r*32
    int buf = 0;

    #pragma unroll
    for (int k = 0; k < 4; ++k) {
        // S(k): stores from tile[buf] (async drain)
        {
            const long obase =
                (((long)((b * ZZ + z) * CC + (cq + k) * 8 + ch)) * HH + h) * WW;
            #pragma unroll
            for (int r = 0; r < 4; ++r) {
                int w4 = wl + r * 32;
                if (w4 < 120) {
                    *reinterpret_cast<float4*>(out1 + obase + (long)w4 * 4)
                        = *reinterpret_cast<const float4*>(&tile[buf][ch * TPAD + w4 * 4]);
                }
            }
        }
        if (k < 3) {
            // zero the other buffer while stores drain
            float4* t4 = reinterpret_cast<float4*>(tile[buf ^ 1]);
            #pragma unroll
            for (int r = 0; r < 4; ++r) {
                int i = tid + r * 256;
                if (i < CTB * TPAD / 4) t4[i] = make_float4(0.f, 0.f, 0.f, 0.f);
            }
            __syncthreads();
            // G(k+1): register-sourced, no global latency
            if (tid < cnt) {
                #pragma unroll
                for (int j = 0; j < 8; ++j) {
                    int c = (cq + k + 1) * 8 + j;
                    float sc = gamma[c] * rsqrtf(rvar[c] + BN_EPS);
                    float bi = beta[c] - rmean[c] * sc;
                    float v = pf.x*W[c*4+0] + pf.y*W[c*4+1] + pf.z*W[c*4+2] + pf.w*W[c*4+3];
                    v = fmaxf(v * sc + bi, 0.0f);
                    atomicMax(reinterpret_cast<unsigned int*>(
                                  &tile[buf ^ 1][j * TPAD + pw]),
                              __float_as_uint(v));
                }
            }
            __syncthreads();
        }
        buf ^= 1;
    }
}

// ---------------- Fallback (round-1 path) if ws too small --------------------
__global__ __launch_bounds__(256) void pfn_fallback(
    const float* __restrict__ feats, const int* __restrict__ coords,
    const float* __restrict__ W, const float* __restrict__ gamma,
    const float* __restrict__ beta, const float* __restrict__ rmean,
    const float* __restrict__ rvar, float* __restrict__ out0,
    float* __restrict__ out1, int N, int B)
{
    long gid = (long)blockIdx.x * blockDim.x + threadIdx.x;
    long total = (long)CC * B * N;
    if (gid >= total) return;
    int n = (int)(gid % N); int rem = (int)(gid / N);
    int b = rem % B; int c = rem / B;
    long pt = (long)b * N + n;
    float4 f = *reinterpret_cast<const float4*>(feats + pt * CIN);
    float scale = gamma[c] * rsqrtf(rvar[c] + BN_EPS);
    float bias  = beta[c] - rmean[c] * scale;
    float val = f.x*W[c*4] + f.y*W[c*4+1] + f.z*W[c*4+2] + f.w*W[c*4+3];
    val = fmaxf(val * scale + bias, 0.0f);
    out0[((long)(b * CC + c)) * N + n] = val;
    int cx = coords[pt*3+0], cy = coords[pt*3+1], cz = coords[pt*3+2];
    long o1 = ((((long)(b * ZZ + cz)) * CC + c) * HH + cx) * WW + cy;
    atomicMax(reinterpret_cast<unsigned int*>(out1) + o1, __float_as_uint(val));
}

extern "C" void kernel_launch(void* const* d_in, const int* in_sizes, int n_in,
                              void* d_out, int out_size, void* d_ws, size_t ws_size,
                              hipStream_t stream) {
    const float* feats  = (const float*)d_in[0];
    const int*   coords = (const int*)d_in[1];
    const float* W      = (const float*)d_in[2];
    const float* gamma  = (const float*)d_in[3];
    const float* beta   = (const float*)d_in[4];
    const float* rmean  = (const float*)d_in[5];
    const float* rvar   = (const float*)d_in[6];

    const int B = 2;
    const int N = in_sizes[0] / (B * CIN);        // 20000

    float* out0 = (float*)d_out;
    long   out0_sz = (long)B * CC * N;
    float* out1 = out0 + out0_sz;

    // ws layout: rowf4 [ROWS*MAXR] float4 | roww [ROWS*MAXR] int | rowcnt [ROWS] int
    const size_t rowf4_bytes = (size_t)ROWS * MAXR * sizeof(float4);  // 7.86 MB
    const size_t roww_bytes  = (size_t)ROWS * MAXR * sizeof(int);     // 1.97 MB
    const size_t cnt_bytes   = (size_t)ROWS * sizeof(int);            // 7.7 KB
    const size_t need = rowf4_bytes + roww_bytes + cnt_bytes;

    if (ws_size >= need) {
        float4* rowf4  = (float4*)d_ws;
        int*    roww   = (int*)((char*)d_ws + rowf4_bytes);
        int*    rowcnt = (int*)((char*)d_ws + rowf4_bytes + roww_bytes);

        pfn_clear_cnt<<<(ROWS + 255) / 256, 256, 0, stream>>>(rowcnt);

        dim3 gridA((B * N + 255) / 256, 8);       // 157 x 8 = 1256 blocks
        pfn_pass_a<<<gridA, 256, 0, stream>>>(
            feats, coords, W, gamma, beta, rmean, rvar, out0,
            rowf4, roww, rowcnt, N, B);

        int blocksB = ROWS * 2;                   // 3840: (row, c-half)
        pfn_pass_b<<<blocksB, 256, 0, stream>>>(
            rowf4, roww, rowcnt, W, gamma, beta, rmean, rvar, out1);
    } else {
        size_t out1_bytes = (size_t)B * ZZ * CC * HH * WW * sizeof(float);
        (void)hipMemsetAsync(out1, 0, out1_bytes, stream);
        long total = (long)CC * B * N;
        pfn_fallback<<<(int)((total + 255) / 256), 256, 0, stream>>>(
            feats, coords, W, gamma, beta, rmean, rvar, out0, out1, N, B);
    }
}